// Round 4
// baseline (428.808 us; speedup 1.0000x reference)
//
#include <hip/hip_runtime.h>
#include <stdint.h>

// ---------------------------------------------------------------------------
// DynamicConv (CondConv x2 + PReLU + self-routing + 1x1 out), MI355X gfx950
// R4: barrier-free K-loop. Weights in LDS (global_load_lds, XOR-swizzled),
//     pixels streamed from global (L1/L2), guard rows, XCD-pinned images.
// ---------------------------------------------------------------------------

typedef _Float16 f16_t;
typedef _Float16 f16x8 __attribute__((ext_vector_type(8)));
typedef _Float16 f16x4 __attribute__((ext_vector_type(4)));
typedef float    f32x4 __attribute__((ext_vector_type(4)));

#define B_   8
#define R_   4
#define C_   64
#define C2_  128
#define H_   128
#define W_   128
#define E_   8
#define RF_  256
#define WP_  130   // padded width  (guard cols at pix 0 and 129)
#define HP_  130   // padded height (guard rows at hp 0 and 129)

__device__ __forceinline__ f32x4 mfma16(f16x8 a, f16x8 b, f32x4 c) {
  return __builtin_amdgcn_mfma_f32_16x16x32_f16(a, b, c, 0, 0, 0);
}

// async global->LDS, 16B per lane; dest must be wave-linear (base + lane*16)
__device__ __forceinline__ void gl16(const f16_t* g, f16_t* l) {
  __builtin_amdgcn_global_load_lds(
      (const __attribute__((address_space(1))) unsigned int*)(const void*)g,
      (__attribute__((address_space(3))) unsigned int*)(void*)l, 16, 0, 0);
}

// ---------- routing weights + zero pooled[4][B][C2] ----------
__global__ void k_rw(const float* __restrict__ routing, const float* __restrict__ rW,
                     const float* __restrict__ rB, float* __restrict__ rw,
                     float* __restrict__ pooled4) {
  int t = threadIdx.x;                 // 256 = R*B*E
  #pragma unroll
  for (int i = 0; i < 16; ++i) pooled4[i*256 + t] = 0.f;
  int e = t & 7, b = (t >> 3) & 7, r = t >> 6;
  float acc = rB[e];
  for (int f = 0; f < RF_; ++f)
    acc += routing[(b*R_ + r)*RF_ + f] * rW[f*E_ + e];
  rw[(r*B_ + b)*E_ + e] = 1.0f / (1.0f + __expf(-acc));
}

// ---------- zero guard rows/cols of xbt (130x130) and xct (130x130) ----------
__global__ void k_zero(f16_t* __restrict__ xbt, f16_t* __restrict__ xct) {
  const f16x8 z = {0,0,0,0,0,0,0,0};
  int t = blockIdx.x*256 + threadIdx.x;
  if (t < 16640) {                       // xbt guard rows: 8b*2*130pix*8slots
    int ch = t & 7, u = t >> 3;
    int pix = u % 130; u /= 130;
    int rs = u & 1, b = u >> 1;
    *(f16x8*)&xbt[((size_t)(b*HP_ + rs*129)*WP_ + pix)*C_ + ch*8] = z;
    return;
  }
  t -= 16640;
  if (t < 33280) {                       // xct guard rows: 8b*2*130pix*16slots
    int ch = t & 15, u = t >> 4;
    int pix = u % 130; u /= 130;
    int rs = u & 1, b = u >> 1;
    *(f16x8*)&xct[((size_t)(b*HP_ + rs*129)*WP_ + pix)*C2_ + ch*8] = z;
    return;
  }
  t -= 33280;
  if (t < 32768) {                       // xct guard cols: 8b*128row*2*16slots
    int ch = t & 15, u = t >> 4;
    int hp = (u & 127) + 1; u >>= 7;
    int cs = u & 1, b = u >> 1;
    *(f16x8*)&xct[((size_t)(b*HP_ + hp)*WP_ + cs*129)*C2_ + ch*8] = z;
  }
}

// ---------- x: NCHW f32 -> padded NHWC f16 (interior rows; guard cols) ------
__global__ void k_xt(const float* __restrict__ x, f16_t* __restrict__ xbt) {
  int wh = blockIdx.x, h = blockIdx.y, b = blockIdx.z;
  int t = threadIdx.x;
  int w0 = wh * 64;
  __shared__ float tile[64][65];
  #pragma unroll
  for (int rep = 0; rep < 16; ++rep) {
    int idx = rep*256 + t;
    int c = idx >> 6, w = idx & 63;
    tile[c][w] = x[((size_t)(b*C_ + c)*H_ + h)*W_ + w0 + w];
  }
  __syncthreads();
  #pragma unroll
  for (int rep = 0; rep < 16; ++rep) {
    int idx = rep*256 + t;
    int w = idx >> 6, c = idx & 63;
    xbt[((size_t)(b*HP_ + h + 1)*WP_ + (w0 + w + 1))*C_ + c] = (f16_t)tile[c][w];
  }
  if (t < 64) {
    if (wh == 0) xbt[((size_t)(b*HP_ + h + 1)*WP_ + 0)*C_ + t]   = (f16_t)0.0f;
    else         xbt[((size_t)(b*HP_ + h + 1)*WP_ + 129)*C_ + t] = (f16_t)0.0f;
  }
}

// ---------- mix1: w1m row=(rb*2+coh)*64+co6, 576 f16/row, XOR-swizzled ------
__global__ void k_mix1(const float* __restrict__ rw, const float* __restrict__ W1,
                       f16_t* __restrict__ w1m) {
  int gid = blockIdx.x*256 + threadIdx.x;    // 589824 total
  int cq = gid & 15;
  int s  = (gid >> 4) % 9;
  int t2 = (gid >> 4) / 9;
  int co = t2 & 127;
  int rb = t2 >> 7;                          // 0..31
  float o0=0.f,o1=0.f,o2=0.f,o3=0.f;
  #pragma unroll
  for (int e = 0; e < E_; ++e) {
    float rv = rw[rb*E_ + e];
    const float* wp = W1 + (size_t)((e*C2_ + co)*C_ + cq*4)*9 + s;
    o0 += rv*wp[0]; o1 += rv*wp[9]; o2 += rv*wp[18]; o3 += rv*wp[27];
  }
  f16x4 pk; pk[0]=(f16_t)o0; pk[1]=(f16_t)o1; pk[2]=(f16_t)o2; pk[3]=(f16_t)o3;
  int coh = co >> 6, co6 = co & 63;
  size_t row = ((size_t)rb*2 + coh)*64 + co6;
  int slot = (s*8 + (cq >> 1)) ^ (co6 & 7);
  *(f16x4*)&w1m[row*576 + slot*8 + (cq & 1)*4] = pk;
}

// ---------- mix2 (+inline srw): w2m row=b*64+co, [cbh][s][c64] swizzled -----
__global__ void k_mix2(const float* __restrict__ pooled_r, const float* __restrict__ srW,
                       const float* __restrict__ srb, const float* __restrict__ W2,
                       f16_t* __restrict__ w2m) {
  __shared__ float sw[64];
  int t = threadIdx.x;
  if (t < 64) {
    int b = t >> 3, e = t & 7;
    float acc = srb[e];
    for (int c = 0; c < C2_; ++c)
      acc += pooled_r[b*C2_ + c] * (1.0f/16384.0f) * srW[c*E_ + e];
    sw[t] = acc;
  }
  __syncthreads();
  int gid = blockIdx.x*256 + t;              // 147456 total
  int c2q = gid & 31;
  int s   = (gid >> 5) % 9;
  int t2  = (gid >> 5) / 9;
  int co  = t2 & 63;
  int b   = t2 >> 6;
  float o0=0.f,o1=0.f,o2=0.f,o3=0.f;
  #pragma unroll
  for (int e = 0; e < E_; ++e) {
    float rv = sw[b*E_ + e];
    const float* wp = W2 + (size_t)((e*C_ + co)*C2_ + c2q*4)*9 + s;
    o0 += rv*wp[0]; o1 += rv*wp[9]; o2 += rv*wp[18]; o3 += rv*wp[27];
  }
  f16x4 pk; pk[0]=(f16_t)o0; pk[1]=(f16_t)o1; pk[2]=(f16_t)o2; pk[3]=(f16_t)o3;
  int cbh = c2q >> 4, c64 = (c2q & 15)*4;
  size_t row = (size_t)b*64 + co;
  int slot = (s*8 + (c64 >> 3)) ^ (co & 7);
  *(f16x4*)&w2m[row*1152 + cbh*576 + slot*8 + (c64 & 7)] = pk;
}

// ---------- conv1: block (b, 2 rows, coh): M=64 x N=256 x K=576 -------------
// A in LDS (staged once, swizzled), B streamed from global. No K-loop barriers.
__global__ __launch_bounds__(256, 2) void k_conv1(
    const f16_t* __restrict__ xbt, const f16_t* __restrict__ w1m,
    const float* __restrict__ pa, f16_t* __restrict__ xct,
    float* __restrict__ pooled_r, int r)
{
  const int bx = blockIdx.x;
  const int b = bx & 7, h0 = (bx >> 3) << 1;     // b in low bits -> XCD pin
  const int coh = blockIdx.y;
  const int tid = threadIdx.x;
  const int lane = tid & 63;
  const int wid = tid >> 6;
  const int wrow = wid >> 1, wph = wid & 1;
  const int l15 = lane & 15, l4 = lane >> 4;
  const int xorv = l15 & 7;
  __shared__ __align__(16) f16_t lA[64 * 576];   // 73,728 B

  const f16_t* w1base = w1m + ((size_t)((r*B_ + b)*2 + coh))*64*576;
  #pragma unroll
  for (int i = 0; i < 18; ++i) {
    int sl = i*256 + tid;
    gl16(w1base + (size_t)sl*8, &lA[sl*8]);
  }

  const f32x4 vzero = {0.f,0.f,0.f,0.f};
  f32x4 acc[4][4];
  #pragma unroll
  for (int i=0;i<4;++i)
    #pragma unroll
    for (int j=0;j<4;++j) acc[i][j] = vzero;

  __syncthreads();   // drain staging; only barrier before epilogue

  const f16_t* xrow0 = xbt + ((size_t)(b*HP_ + h0 + wrow)*WP_)*C_;
  const int pbase = wph*64 + l15;

  #pragma unroll
  for (int cb = 0; cb < 2; ++cb) {
    #pragma unroll
    for (int dh = 0; dh < 3; ++dh) {
      const f16_t* xr = xrow0 + (size_t)dh*WP_*C_ + cb*32 + l4*8;
      #pragma unroll
      for (int dw = 0; dw < 3; ++dw) {
        const int slot = ((dh*3 + dw)*8 + cb*4 + l4) ^ xorv;
        f16x8 af[4], bf[4];
        #pragma unroll
        for (int fm = 0; fm < 4; ++fm)
          af[fm] = *(const f16x8*)&lA[(fm*16 + l15)*576 + slot*8];
        #pragma unroll
        for (int fn = 0; fn < 4; ++fn)
          bf[fn] = *(const f16x8*)(xr + (size_t)(pbase + fn*16 + dw)*C_);
        __builtin_amdgcn_s_setprio(1);
        #pragma unroll
        for (int fm = 0; fm < 4; ++fm)
          #pragma unroll
          for (int fn = 0; fn < 4; ++fn)
            acc[fm][fn] = mfma16(af[fm], bf[fn], acc[fm][fn]);
        __builtin_amdgcn_s_setprio(0);
      }
    }
  }

  // epilogue: PReLU, pooled partials, transpose-store via LDS (reuse lA)
  const float a = pa[0];
  float ps[4][4];
  #pragma unroll
  for (int fm=0;fm<4;++fm)
    #pragma unroll
    for (int j=0;j<4;++j) ps[fm][j] = 0.f;
  #pragma unroll
  for (int fm = 0; fm < 4; ++fm)
    #pragma unroll
    for (int fn = 0; fn < 4; ++fn)
      #pragma unroll
      for (int j = 0; j < 4; ++j) {
        float v = acc[fm][fn][j];
        v = (v >= 0.f) ? v : a*v;
        acc[fm][fn][j] = v;
        ps[fm][j] += v;
      }
  #pragma unroll
  for (int fm = 0; fm < 4; ++fm)
    #pragma unroll
    for (int j = 0; j < 4; ++j) {
      float s = ps[fm][j];
      s += __shfl_xor(s, 1, 64);
      s += __shfl_xor(s, 2, 64);
      s += __shfl_xor(s, 4, 64);
      s += __shfl_xor(s, 8, 64);
      ps[fm][j] = s;                 // valid on l15==0 lanes
    }
  __syncthreads();                   // done reading lA for MFMA
  f16_t* lso = lA;                   // [256 pix][72]
  float* lps = (float*)(lA + 256*72);
  const int prow = wrow*128 + wph*64;
  #pragma unroll
  for (int fm = 0; fm < 4; ++fm)
    #pragma unroll
    for (int fn = 0; fn < 4; ++fn) {
      f16x4 pk;
      #pragma unroll
      for (int j = 0; j < 4; ++j) pk[j] = (f16_t)acc[fm][fn][j];
      *(f16x4*)&lso[(prow + fn*16 + l15)*72 + fm*16 + l4*4] = pk;
    }
  if (l15 == 0) {
    #pragma unroll
    for (int fm = 0; fm < 4; ++fm)
      #pragma unroll
      for (int j = 0; j < 4; ++j)
        lps[wid*64 + fm*16 + l4*4 + j] = ps[fm][j];
  }
  __syncthreads();
  #pragma unroll
  for (int p = 0; p < 8; ++p) {
    int i = p*256 + tid;
    int pl = i >> 3, q = i & 7;
    int row = pl >> 7, pix = pl & 127;
    uint4 v = *(const uint4*)&lso[pl*72 + q*8];
    *(uint4*)(xct + ((size_t)(b*HP_ + h0 + row + 1)*WP_ + pix + 1)*C2_ + coh*64 + q*8) = v;
  }
  if (tid < 64) {
    float s = lps[tid] + lps[64 + tid] + lps[128 + tid] + lps[192 + tid];
    atomicAdd(&pooled_r[b*C2_ + coh*64 + tid], s);
  }
}

// ---------- conv2 + PReLU + 1x1 Wout: block (b, 2 rows): 64 x 256 x 1152 ----
__global__ __launch_bounds__(256, 2) void k_conv2(
    const f16_t* __restrict__ xct, const f16_t* __restrict__ w2m,
    const float* __restrict__ pa, const float* __restrict__ Wout,
    const float* __restrict__ bout, float* __restrict__ out, int r)
{
  const int bx = blockIdx.x;
  const int b = bx & 7, h0 = (bx >> 3) << 1;
  const int tid = threadIdx.x;
  const int lane = tid & 63;
  const int wid = tid >> 6;
  const int wrow = wid >> 1, wph = wid & 1;
  const int l15 = lane & 15, l4 = lane >> 4;
  const int xorv = l15 & 7;
  __shared__ __align__(16) f16_t lA[64 * 576];   // one K-half

  const f16_t* w2base = w2m + (size_t)b*64*1152;
  const f32x4 vzero = {0.f,0.f,0.f,0.f};
  f32x4 acc[4][4];
  #pragma unroll
  for (int i=0;i<4;++i)
    #pragma unroll
    for (int j=0;j<4;++j) acc[i][j] = vzero;

  const f16_t* xrow0 = xct + ((size_t)(b*HP_ + h0 + wrow)*WP_)*C2_;
  const int pbase = wph*64 + l15;

  #pragma unroll
  for (int cbh = 0; cbh < 2; ++cbh) {
    if (cbh) __syncthreads();        // all waves done reading half 0
    #pragma unroll
    for (int i = 0; i < 18; ++i) {
      int sl = i*256 + tid;
      int rr = sl / 72, j = sl - rr*72;
      gl16(w2base + (size_t)rr*1152 + cbh*576 + j*8, &lA[sl*8]);
    }
    __syncthreads();                 // drain staging
    #pragma unroll
    for (int cb = 0; cb < 2; ++cb) {
      #pragma unroll
      for (int dh = 0; dh < 3; ++dh) {
        const f16_t* xr = xrow0 + (size_t)dh*WP_*C2_ + cbh*64 + cb*32 + l4*8;
        #pragma unroll
        for (int dw = 0; dw < 3; ++dw) {
          const int slot = ((dh*3 + dw)*8 + cb*4 + l4) ^ xorv;
          f16x8 af[4], bf[4];
          #pragma unroll
          for (int fm = 0; fm < 4; ++fm)
            af[fm] = *(const f16x8*)&lA[(fm*16 + l15)*576 + slot*8];
          #pragma unroll
          for (int fn = 0; fn < 4; ++fn)
            bf[fn] = *(const f16x8*)(xr + (size_t)(pbase + fn*16 + dw)*C2_);
          __builtin_amdgcn_s_setprio(1);
          #pragma unroll
          for (int fm = 0; fm < 4; ++fm)
            #pragma unroll
            for (int fn = 0; fn < 4; ++fn)
              acc[fm][fn] = mfma16(af[fm], bf[fn], acc[fm][fn]);
          __builtin_amdgcn_s_setprio(0);
        }
      }
    }
  }

  // epilogue: PReLU + Wout reduce
  const float a  = pa[0];
  const float bo = bout[0];
  float wr_[4][4];
  #pragma unroll
  for (int fm = 0; fm < 4; ++fm)
    #pragma unroll
    for (int j = 0; j < 4; ++j)
      wr_[fm][j] = Wout[fm*16 + l4*4 + j];
  float* orow = out + ((size_t)((b*R_ + r)*H_ + h0 + wrow))*W_;
  #pragma unroll
  for (int fn = 0; fn < 4; ++fn) {
    float s = 0.f;
    #pragma unroll
    for (int fm = 0; fm < 4; ++fm)
      #pragma unroll
      for (int j = 0; j < 4; ++j) {
        float v = acc[fm][fn][j];
        v = (v >= 0.f) ? v : a*v;
        s += wr_[fm][j]*v;
      }
    s += __shfl_xor(s, 16, 64);
    s += __shfl_xor(s, 32, 64);
    if (lane < 16)
      orow[wph*64 + fn*16 + lane] = s + bo;
  }
}

// ---------------------------------------------------------------------------
extern "C" void kernel_launch(void* const* d_in, const int* in_sizes, int n_in,
                              void* d_out, int out_size, void* d_ws, size_t ws_size,
                              hipStream_t stream) {
  (void)in_sizes; (void)n_in; (void)out_size; (void)ws_size;
  const float* x       = (const float*)d_in[0];
  const float* routing = (const float*)d_in[1];
  const float* rW      = (const float*)d_in[2];
  const float* rB      = (const float*)d_in[3];
  const float* W1      = (const float*)d_in[4];
  const float* pa      = (const float*)d_in[5];
  const float* W2      = (const float*)d_in[6];
  const float* srW     = (const float*)d_in[7];
  const float* srb     = (const float*)d_in[8];
  const float* Wout    = (const float*)d_in[9];
  const float* bout    = (const float*)d_in[10];
  float* out = (float*)d_out;

  char* ws = (char*)d_ws;
  size_t off = 0;
  f16_t* xbt = (f16_t*)(ws + off); off += (size_t)B_*HP_*WP_*C_*2;   // 17,305,600
  f16_t* w1m = (f16_t*)(ws + off); off += (size_t)32*2*64*576*2;     //  4,718,592
  f16_t* xct = (f16_t*)(ws + off); off += (size_t)B_*HP_*WP_*C2_*2;  // 34,611,200
  f16_t* w2m = (f16_t*)(ws + off); off += (size_t)B_*64*1152*2;      //  1,179,648
  float* rw     = (float*)(ws + off); off += (size_t)R_*B_*E_*4;
  float* pooled = (float*)(ws + off); off += (size_t)R_*B_*C2_*4;
  // total ~57.8 MB of d_ws

  k_rw  <<<1, 256, 0, stream>>>(routing, rW, rB, rw, pooled);
  k_zero<<<323, 256, 0, stream>>>(xbt, xct);
  k_xt  <<<dim3(2, H_, B_), 256, 0, stream>>>(x, xbt);
  k_mix1<<<2304, 256, 0, stream>>>(rw, W1, w1m);
  for (int r = 0; r < R_; ++r) {
    float* pooled_r = pooled + (size_t)r*B_*C2_;
    k_conv1<<<dim3(512, 2), 256, 0, stream>>>(xbt, w1m, pa, xct, pooled_r, r);
    k_mix2 <<<576, 256, 0, stream>>>(pooled_r, srW, srb, W2, w2m);
    k_conv2<<<dim3(512), 256, 0, stream>>>(xct, w2m, pa, Wout, bout, out, r);
  }
}

// Round 5
// 293.226 us; speedup vs baseline: 1.4624x; 1.4624x over previous
//
#include <hip/hip_runtime.h>
#include <stdint.h>

// ---------------------------------------------------------------------------
// DynamicConv (CondConv x2 + PReLU + self-routing + 1x1 out), MI355X gfx950
// R5: LDS-staged A+B via global_load_lds (async DMA), sigma-XOR swizzled
//     layouts (pre-swizzled sources, linear LDS dest), XCD-pinned images,
//     2 blocks/CU. 2 barriers per K-chunk, DMA-issue staging.
// ---------------------------------------------------------------------------

typedef _Float16 f16_t;
typedef _Float16 f16x8 __attribute__((ext_vector_type(8)));
typedef _Float16 f16x4 __attribute__((ext_vector_type(4)));
typedef float    f32x4 __attribute__((ext_vector_type(4)));

#define B_   8
#define R_   4
#define C_   64
#define C2_  128
#define H_   128
#define W_   128
#define E_   8
#define RF_  256
#define WP_  130   // padded width  (guard cols at pix 0 and 129)
#define HP_  130   // padded height (guard rows at hp 0 and 129)

__device__ __forceinline__ f32x4 mfma16(f16x8 a, f16x8 b, f32x4 c) {
  return __builtin_amdgcn_mfma_f32_16x16x32_f16(a, b, c, 0, 0, 0);
}

// async global->LDS, 16B per lane; dest must be wave-linear (base + lane*16)
__device__ __forceinline__ void gl16(const f16_t* g, f16_t* l) {
  __builtin_amdgcn_global_load_lds(
      (const __attribute__((address_space(1))) unsigned int*)(const void*)g,
      (__attribute__((address_space(3))) unsigned int*)(void*)l, 16, 0, 0);
}

__device__ __host__ __forceinline__ int sig(int n) { return (n ^ (n >> 2)) & 3; }

// ---------- routing weights + zero pooled[4][B][C2] ----------
__global__ void k_rw(const float* __restrict__ routing, const float* __restrict__ rW,
                     const float* __restrict__ rB, float* __restrict__ rw,
                     float* __restrict__ pooled4) {
  int t = threadIdx.x;                 // 256 = R*B*E
  #pragma unroll
  for (int i = 0; i < 16; ++i) pooled4[i*256 + t] = 0.f;
  int e = t & 7, b = (t >> 3) & 7, r = t >> 6;
  float acc = rB[e];
  for (int f = 0; f < RF_; ++f)
    acc += routing[(b*R_ + r)*RF_ + f] * rW[f*E_ + e];
  rw[(r*B_ + b)*E_ + e] = 1.0f / (1.0f + __expf(-acc));
}

// ---------- zero guard rows/cols of xbt (130x130) and xct (130x130) ----------
__global__ void k_zero(f16_t* __restrict__ xbt, f16_t* __restrict__ xct) {
  const f16x8 z = {0,0,0,0,0,0,0,0};
  int t = blockIdx.x*256 + threadIdx.x;
  if (t < 16640) {                       // xbt guard rows: 8b*2*130pix*8slots
    int ch = t & 7, u = t >> 3;
    int pix = u % 130; u /= 130;
    int rs = u & 1, b = u >> 1;
    *(f16x8*)&xbt[((size_t)(b*HP_ + rs*129)*WP_ + pix)*C_ + ch*8] = z;
    return;
  }
  t -= 16640;
  if (t < 33280) {                       // xct guard rows: 8b*2*130pix*16slots
    int ch = t & 15, u = t >> 4;
    int pix = u % 130; u /= 130;
    int rs = u & 1, b = u >> 1;
    *(f16x8*)&xct[((size_t)(b*HP_ + rs*129)*WP_ + pix)*C2_ + ch*8] = z;
    return;
  }
  t -= 33280;
  if (t < 32768) {                       // xct guard cols: 8b*128row*2*16slots
    int ch = t & 15, u = t >> 4;
    int hp = (u & 127) + 1; u >>= 7;
    int cs = u & 1, b = u >> 1;
    *(f16x8*)&xct[((size_t)(b*HP_ + hp)*WP_ + cs*129)*C2_ + ch*8] = z;
  }
}

// ---------- x: NCHW f32 -> padded NHWC f16 (interior rows; guard cols) ------
__global__ void k_xt(const float* __restrict__ x, f16_t* __restrict__ xbt) {
  int wh = blockIdx.x, h = blockIdx.y, b = blockIdx.z;
  int t = threadIdx.x;
  int w0 = wh * 64;
  __shared__ float tile[64][65];
  #pragma unroll
  for (int rep = 0; rep < 16; ++rep) {
    int idx = rep*256 + t;
    int c = idx >> 6, w = idx & 63;
    tile[c][w] = x[((size_t)(b*C_ + c)*H_ + h)*W_ + w0 + w];
  }
  __syncthreads();
  #pragma unroll
  for (int rep = 0; rep < 16; ++rep) {
    int idx = rep*256 + t;
    int w = idx >> 6, c = idx & 63;
    xbt[((size_t)(b*HP_ + h + 1)*WP_ + (w0 + w + 1))*C_ + c] = (f16_t)tile[c][w];
  }
  if (t < 64) {
    if (wh == 0) xbt[((size_t)(b*HP_ + h + 1)*WP_ + 0)*C_ + t]   = (f16_t)0.0f;
    else         xbt[((size_t)(b*HP_ + h + 1)*WP_ + 129)*C_ + t] = (f16_t)0.0f;
  }
}

// ---------- mix1: w1m row = ((rb*2+coh)*2+cb)*64+co6, 288 f16/row -----------
// unit layout within row: s*4 + (cq ^ sig(co6)), each unit = 8 ch f16
__global__ void k_mix1(const float* __restrict__ rw, const float* __restrict__ W1,
                       f16_t* __restrict__ w1m) {
  int gid = blockIdx.x*256 + threadIdx.x;    // 589824 total
  int cq4 = gid & 15;                        // ch quad: ch = cq4*4 .. +3
  int s   = (gid >> 4) % 9;
  int t2  = (gid >> 4) / 9;
  int co  = t2 & 127;
  int rb  = t2 >> 7;                         // 0..31
  float o0=0.f,o1=0.f,o2=0.f,o3=0.f;
  #pragma unroll
  for (int e = 0; e < E_; ++e) {
    float rv = rw[rb*E_ + e];
    const float* wp = W1 + (size_t)((e*C2_ + co)*C_ + cq4*4)*9 + s;
    o0 += rv*wp[0]; o1 += rv*wp[9]; o2 += rv*wp[18]; o3 += rv*wp[27];
  }
  f16x4 pk; pk[0]=(f16_t)o0; pk[1]=(f16_t)o1; pk[2]=(f16_t)o2; pk[3]=(f16_t)o3;
  int coh = co >> 6, co6 = co & 63;
  int cb  = cq4 >> 3;
  int cqu = (cq4 >> 1) & 3;
  int off = (cq4 & 1) * 4;
  size_t row = ((size_t)(rb*2 + coh)*2 + cb)*64 + co6;
  *(f16x4*)&w1m[row*288 + (size_t)(s*4 + (cqu ^ sig(co6)))*8 + off] = pk;
}

// ---------- mix2 (+inline srw): w2m row = (b*4+it)*64+co, 288 f16/row -------
__global__ void k_mix2(const float* __restrict__ pooled_r, const float* __restrict__ srW,
                       const float* __restrict__ srb, const float* __restrict__ W2,
                       f16_t* __restrict__ w2m) {
  __shared__ float sw[64];
  int t = threadIdx.x;
  if (t < 64) {
    int b = t >> 3, e = t & 7;
    float acc = srb[e];
    for (int c = 0; c < C2_; ++c)
      acc += pooled_r[b*C2_ + c] * (1.0f/16384.0f) * srW[c*E_ + e];
    sw[t] = acc;
  }
  __syncthreads();
  int gid = blockIdx.x*256 + t;              // 147456 total
  int c2q = gid & 31;                        // ch quad: ch = c2q*4 .. +3
  int s   = (gid >> 5) % 9;
  int t2  = (gid >> 5) / 9;
  int co  = t2 & 63;
  int b   = t2 >> 6;
  float o0=0.f,o1=0.f,o2=0.f,o3=0.f;
  #pragma unroll
  for (int e = 0; e < E_; ++e) {
    float rv = sw[b*E_ + e];
    const float* wp = W2 + (size_t)((e*C_ + co)*C2_ + c2q*4)*9 + s;
    o0 += rv*wp[0]; o1 += rv*wp[9]; o2 += rv*wp[18]; o3 += rv*wp[27];
  }
  f16x4 pk; pk[0]=(f16_t)o0; pk[1]=(f16_t)o1; pk[2]=(f16_t)o2; pk[3]=(f16_t)o3;
  int it  = c2q >> 3;
  int cqu = (c2q >> 1) & 3;
  int off = (c2q & 1) * 4;
  size_t row = ((size_t)b*4 + it)*64 + co;
  *(f16x4*)&w2m[row*288 + (size_t)(s*4 + (cqu ^ sig(co)))*8 + off] = pk;
}

// ---------- conv1: block (b, coh, 2 rows): M=64 x N=256 x K=576 -------------
// A+B staged via global_load_lds; sigma-swizzled units; 2 cb chunks.
__global__ __launch_bounds__(256, 2) void k_conv1(
    const f16_t* __restrict__ xbt, const f16_t* __restrict__ w1m,
    const float* __restrict__ pa, f16_t* __restrict__ xct,
    float* __restrict__ pooled_r, int r)
{
  const int bx = blockIdx.x;
  const int b = bx & 7, h0 = (bx >> 3) << 1;     // b in low bits -> XCD pin
  const int coh = blockIdx.y;
  const int tid = threadIdx.x;
  const int lane = tid & 63;
  const int wid = tid >> 6;
  const int wrow = wid >> 1, wph = wid & 1;      // output row, pixel half
  const int l15 = lane & 15, l4 = lane >> 4;
  __shared__ __align__(16) f16_t lA[64*288];     // 36,864 B
  __shared__ __align__(16) f16_t lB[2080*8];     // 33,280 B (total 70,144)

  const int xorA = (l4 ^ sig(l15)) << 4;         // byte offset within A unit group
  int bbase[3];                                  // per-dw B byte base
  #pragma unroll
  for (int dw = 0; dw < 3; ++dw) {
    int P0 = wph*64 + dw + l15;
    bbase[dw] = P0*64 + ((l4 ^ sig(P0)) << 4);
  }

  const f32x4 vzero = {0.f,0.f,0.f,0.f};
  f32x4 acc[4][4];
  #pragma unroll
  for (int i=0;i<4;++i)
    #pragma unroll
    for (int j=0;j<4;++j) acc[i][j] = vzero;

  const int rb = r*B_ + b;
  const f16_t* w1base = w1m + ((size_t)(rb*2 + coh)*2)*64*288;
  const f16_t* xb = xbt + ((size_t)(b*HP_ + h0))*WP_*C_;  // local row 0 = hp h0

  for (int cb = 0; cb < 2; ++cb) {
    __syncthreads();                   // previous reads done / first entry
    // stage A: 2304 linear units (w1m pre-swizzled)
    #pragma unroll
    for (int k = 0; k < 9; ++k) {
      int u = k*256 + tid;
      gl16(w1base + (size_t)cb*64*288 + (size_t)u*8, &lA[u*8]);
    }
    // stage B: 2080 units, per-lane source swizzle, linear LDS dest
    #pragma unroll
    for (int k = 0; k < 8; ++k) {
      int u = k*256 + tid;
      int row = u / 520, rem = u - row*520;
      int pix = rem >> 2, cq = (rem & 3) ^ sig(pix);
      gl16(xb + ((size_t)row*WP_ + pix)*C_ + cb*32 + cq*8, &lB[u*8]);
    }
    if (tid < 32) {                    // tail 32 units (lane0 active -> safe)
      int u = 2048 + tid;
      int rem = u - 1560;              // row 3
      int pix = rem >> 2, cq = (rem & 3) ^ sig(pix);
      gl16(xb + ((size_t)3*WP_ + pix)*C_ + cb*32 + cq*8, &lB[u*8]);
    }
    __syncthreads();                   // drains vmcnt (compiler waitcnt) + barrier
    __builtin_amdgcn_s_setprio(1);
    #pragma unroll
    for (int dh = 0; dh < 3; ++dh) {
      #pragma unroll
      for (int dw = 0; dw < 3; ++dw) {
        const int s = dh*3 + dw;
        f16x8 af[4], bf[4];
        #pragma unroll
        for (int fm = 0; fm < 4; ++fm)
          af[fm] = *(const f16x8*)((const char*)lA + (fm*16 + l15)*576 + s*64 + xorA);
        #pragma unroll
        for (int fn = 0; fn < 4; ++fn)
          bf[fn] = *(const f16x8*)((const char*)lB + (wrow + dh)*8320 + bbase[dw] + fn*1024);
        #pragma unroll
        for (int fm = 0; fm < 4; ++fm)
          #pragma unroll
          for (int fn = 0; fn < 4; ++fn)
            acc[fm][fn] = mfma16(af[fm], bf[fn], acc[fm][fn]);
      }
    }
    __builtin_amdgcn_s_setprio(0);
  }

  // epilogue: PReLU, pooled partials, transpose-store via LDS (reuse lA/lB)
  const float a = pa[0];
  float ps[4][4];
  #pragma unroll
  for (int fm=0;fm<4;++fm)
    #pragma unroll
    for (int j=0;j<4;++j) ps[fm][j] = 0.f;
  #pragma unroll
  for (int fm = 0; fm < 4; ++fm)
    #pragma unroll
    for (int fn = 0; fn < 4; ++fn)
      #pragma unroll
      for (int j = 0; j < 4; ++j) {
        float v = acc[fm][fn][j];
        v = (v >= 0.f) ? v : a*v;
        acc[fm][fn][j] = v;
        ps[fm][j] += v;
      }
  #pragma unroll
  for (int fm = 0; fm < 4; ++fm)
    #pragma unroll
    for (int j = 0; j < 4; ++j) {
      float s = ps[fm][j];
      s += __shfl_xor(s, 1, 64);
      s += __shfl_xor(s, 2, 64);
      s += __shfl_xor(s, 4, 64);
      s += __shfl_xor(s, 8, 64);
      ps[fm][j] = s;                   // valid on l15==0 lanes
    }
  __syncthreads();                     // done reading lA/lB for MFMA
  f16_t* lso = lA;                     // [256 pix][72]
  float* lps = (float*)lB;             // 4 waves x 64 ch partials
  const int prow = wrow*128 + wph*64;
  #pragma unroll
  for (int fm = 0; fm < 4; ++fm)
    #pragma unroll
    for (int fn = 0; fn < 4; ++fn) {
      f16x4 pk;
      #pragma unroll
      for (int j = 0; j < 4; ++j) pk[j] = (f16_t)acc[fm][fn][j];
      *(f16x4*)&lso[(prow + fn*16 + l15)*72 + fm*16 + l4*4] = pk;
    }
  if (l15 == 0) {
    #pragma unroll
    for (int fm = 0; fm < 4; ++fm)
      #pragma unroll
      for (int j = 0; j < 4; ++j)
        lps[wid*64 + fm*16 + l4*4 + j] = ps[fm][j];
  }
  __syncthreads();
  #pragma unroll
  for (int p = 0; p < 8; ++p) {
    int i = p*256 + tid;
    int pl = i >> 3, q = i & 7;
    int row = pl >> 7, pix = pl & 127;
    uint4 v = *(const uint4*)&lso[pl*72 + q*8];
    *(uint4*)(xct + ((size_t)(b*HP_ + h0 + row + 1)*WP_ + pix + 1)*C2_ + coh*64 + q*8) = v;
  }
  if (tid < 64) {
    float s = lps[tid] + lps[64 + tid] + lps[128 + tid] + lps[192 + tid];
    atomicAdd(&pooled_r[b*C2_ + coh*64 + tid], s);
  }
}

// ---------- conv2 + PReLU + 1x1 Wout: block (b, 2 rows): 64 x 256 x 1152 ----
__global__ __launch_bounds__(256, 2) void k_conv2(
    const f16_t* __restrict__ xct, const f16_t* __restrict__ w2m,
    const float* __restrict__ pa, const float* __restrict__ Wout,
    const float* __restrict__ bout, float* __restrict__ out, int r)
{
  const int bx = blockIdx.x;
  const int b = bx & 7, h0 = (bx >> 3) << 1;
  const int tid = threadIdx.x;
  const int lane = tid & 63;
  const int wid = tid >> 6;
  const int wrow = wid >> 1, wph = wid & 1;
  const int l15 = lane & 15, l4 = lane >> 4;
  __shared__ __align__(16) f16_t lA[64*288];
  __shared__ __align__(16) f16_t lB[2080*8];

  const int xorA = (l4 ^ sig(l15)) << 4;
  int bbase[3];
  #pragma unroll
  for (int dw = 0; dw < 3; ++dw) {
    int P0 = wph*64 + dw + l15;
    bbase[dw] = P0*64 + ((l4 ^ sig(P0)) << 4);
  }

  const f32x4 vzero = {0.f,0.f,0.f,0.f};
  f32x4 acc[4][4];
  #pragma unroll
  for (int i=0;i<4;++i)
    #pragma unroll
    for (int j=0;j<4;++j) acc[i][j] = vzero;

  const f16_t* w2base = w2m + (size_t)b*4*64*288;
  const f16_t* xb = xct + ((size_t)(b*HP_ + h0))*WP_*C2_;

  for (int it = 0; it < 4; ++it) {     // K chunks of 32 ch (over 128)
    __syncthreads();
    #pragma unroll
    for (int k = 0; k < 9; ++k) {
      int u = k*256 + tid;
      gl16(w2base + (size_t)it*64*288 + (size_t)u*8, &lA[u*8]);
    }
    #pragma unroll
    for (int k = 0; k < 8; ++k) {
      int u = k*256 + tid;
      int row = u / 520, rem = u - row*520;
      int pix = rem >> 2, cq = (rem & 3) ^ sig(pix);
      gl16(xb + ((size_t)row*WP_ + pix)*C2_ + it*32 + cq*8, &lB[u*8]);
    }
    if (tid < 32) {
      int u = 2048 + tid;
      int rem = u - 1560;
      int pix = rem >> 2, cq = (rem & 3) ^ sig(pix);
      gl16(xb + ((size_t)3*WP_ + pix)*C2_ + it*32 + cq*8, &lB[u*8]);
    }
    __syncthreads();
    __builtin_amdgcn_s_setprio(1);
    #pragma unroll
    for (int dh = 0; dh < 3; ++dh) {
      #pragma unroll
      for (int dw = 0; dw < 3; ++dw) {
        const int s = dh*3 + dw;
        f16x8 af[4], bf[4];
        #pragma unroll
        for (int fm = 0; fm < 4; ++fm)
          af[fm] = *(const f16x8*)((const char*)lA + (fm*16 + l15)*576 + s*64 + xorA);
        #pragma unroll
        for (int fn = 0; fn < 4; ++fn)
          bf[fn] = *(const f16x8*)((const char*)lB + (wrow + dh)*8320 + bbase[dw] + fn*1024);
        #pragma unroll
        for (int fm = 0; fm < 4; ++fm)
          #pragma unroll
          for (int fn = 0; fn < 4; ++fn)
            acc[fm][fn] = mfma16(af[fm], bf[fn], acc[fm][fn]);
      }
    }
    __builtin_amdgcn_s_setprio(0);
  }

  // epilogue: PReLU + Wout reduce
  const float a  = pa[0];
  const float bo = bout[0];
  float wr_[4][4];
  #pragma unroll
  for (int fm = 0; fm < 4; ++fm)
    #pragma unroll
    for (int j = 0; j < 4; ++j)
      wr_[fm][j] = Wout[fm*16 + l4*4 + j];
  float* orow = out + ((size_t)((b*R_ + r)*H_ + h0 + wrow))*W_;
  #pragma unroll
  for (int fn = 0; fn < 4; ++fn) {
    float s = 0.f;
    #pragma unroll
    for (int fm = 0; fm < 4; ++fm)
      #pragma unroll
      for (int j = 0; j < 4; ++j) {
        float v = acc[fm][fn][j];
        v = (v >= 0.f) ? v : a*v;
        s += wr_[fm][j]*v;
      }
    s += __shfl_xor(s, 16, 64);
    s += __shfl_xor(s, 32, 64);
    if (lane < 16)
      orow[wph*64 + fn*16 + lane] = s + bo;
  }
}

// ---------------------------------------------------------------------------
extern "C" void kernel_launch(void* const* d_in, const int* in_sizes, int n_in,
                              void* d_out, int out_size, void* d_ws, size_t ws_size,
                              hipStream_t stream) {
  (void)in_sizes; (void)n_in; (void)out_size; (void)ws_size;
  const float* x       = (const float*)d_in[0];
  const float* routing = (const float*)d_in[1];
  const float* rW      = (const float*)d_in[2];
  const float* rB      = (const float*)d_in[3];
  const float* W1      = (const float*)d_in[4];
  const float* pa      = (const float*)d_in[5];
  const float* W2      = (const float*)d_in[6];
  const float* srW     = (const float*)d_in[7];
  const float* srb     = (const float*)d_in[8];
  const float* Wout    = (const float*)d_in[9];
  const float* bout    = (const float*)d_in[10];
  float* out = (float*)d_out;

  char* ws = (char*)d_ws;
  size_t off = 0;
  f16_t* xbt = (f16_t*)(ws + off); off += (size_t)B_*HP_*WP_*C_*2;   // 17,305,600
  f16_t* w1m = (f16_t*)(ws + off); off += (size_t)8192*288*2;        //  4,718,592
  f16_t* xct = (f16_t*)(ws + off); off += (size_t)B_*HP_*WP_*C2_*2;  // 34,611,200
  f16_t* w2m = (f16_t*)(ws + off); off += (size_t)2048*288*2;        //  1,179,648
  float* rw     = (float*)(ws + off); off += (size_t)R_*B_*E_*4;
  float* pooled = (float*)(ws + off); off += (size_t)R_*B_*C2_*4;
  // total ~57.8 MB of d_ws

  k_rw  <<<1, 256, 0, stream>>>(routing, rW, rB, rw, pooled);
  k_zero<<<323, 256, 0, stream>>>(xbt, xct);
  k_xt  <<<dim3(2, H_, B_), 256, 0, stream>>>(x, xbt);
  k_mix1<<<2304, 256, 0, stream>>>(rw, W1, w1m);
  for (int r = 0; r < R_; ++r) {
    float* pooled_r = pooled + (size_t)r*B_*C2_;
    k_conv1<<<dim3(512, 2), 256, 0, stream>>>(xbt, w1m, pa, xct, pooled_r, r);
    k_mix2 <<<576, 256, 0, stream>>>(pooled_r, srW, srb, W2, w2m);
    k_conv2<<<dim3(512), 256, 0, stream>>>(xct, w2m, pa, Wout, bout, out, r);
  }
}

// Round 6
// 242.849 us; speedup vs baseline: 1.7657x; 1.2074x over previous
//
#include <hip/hip_runtime.h>
#include <stdint.h>

// ---------------------------------------------------------------------------
// DynamicConv (CondConv x2 + PReLU + self-routing + 1x1 out), MI355X gfx950
// R6: r-loop fused into fat dispatches (per-r xct/w2m buffers), 7 launches.
//     Conv bodies identical to R5 (LDS DMA staging, sigma-swizzle, XCD pin).
// ---------------------------------------------------------------------------

typedef _Float16 f16_t;
typedef _Float16 f16x8 __attribute__((ext_vector_type(8)));
typedef _Float16 f16x4 __attribute__((ext_vector_type(4)));
typedef float    f32x4 __attribute__((ext_vector_type(4)));

#define B_   8
#define R_   4
#define C_   64
#define C2_  128
#define H_   128
#define W_   128
#define E_   8
#define RF_  256
#define WP_  130   // padded width  (guard cols at pix 0 and 129)
#define HP_  130   // padded height (guard rows at hp 0 and 129)

__device__ __forceinline__ f32x4 mfma16(f16x8 a, f16x8 b, f32x4 c) {
  return __builtin_amdgcn_mfma_f32_16x16x32_f16(a, b, c, 0, 0, 0);
}

// async global->LDS, 16B per lane; dest must be wave-linear (base + lane*16)
__device__ __forceinline__ void gl16(const f16_t* g, f16_t* l) {
  __builtin_amdgcn_global_load_lds(
      (const __attribute__((address_space(1))) unsigned int*)(const void*)g,
      (__attribute__((address_space(3))) unsigned int*)(void*)l, 16, 0, 0);
}

__device__ __host__ __forceinline__ int sig(int n) { return (n ^ (n >> 2)) & 3; }

// ---------- routing weights + zero pooled[4][B][C2] ----------
__global__ void k_rw(const float* __restrict__ routing, const float* __restrict__ rW,
                     const float* __restrict__ rB, float* __restrict__ rw,
                     float* __restrict__ pooled4) {
  int t = threadIdx.x;                 // 256 = R*B*E
  #pragma unroll
  for (int i = 0; i < 16; ++i) pooled4[i*256 + t] = 0.f;
  int e = t & 7, b = (t >> 3) & 7, r = t >> 6;
  float acc = rB[e];
  for (int f = 0; f < RF_; ++f)
    acc += routing[(b*R_ + r)*RF_ + f] * rW[f*E_ + e];
  rw[(r*B_ + b)*E_ + e] = 1.0f / (1.0f + __expf(-acc));
}

// ---------- zero guard rows/cols of xbt and all-r xct (130x130) --------------
__global__ void k_zero(f16_t* __restrict__ xbt, f16_t* __restrict__ xct,
                       size_t xct_stride) {
  const f16x8 z = {0,0,0,0,0,0,0,0};
  int t = blockIdx.x*256 + threadIdx.x;
  if (t < 16640) {                       // xbt guard rows: 8b*2*130pix*8slots
    int ch = t & 7, u = t >> 3;
    int pix = u % 130; u /= 130;
    int rs = u & 1, b = u >> 1;
    *(f16x8*)&xbt[((size_t)(b*HP_ + rs*129)*WP_ + pix)*C_ + ch*8] = z;
    return;
  }
  t -= 16640;
  if (t < 133120) {                      // xct guard rows: 4r*8b*2*130pix*16slots
    int ch = t & 15, u = t >> 4;
    int pix = u % 130; u /= 130;
    int rs = u & 1; u >>= 1;
    int b = u & 7, r = u >> 3;
    *(f16x8*)&xct[(size_t)r*xct_stride + ((size_t)(b*HP_ + rs*129)*WP_ + pix)*C2_ + ch*8] = z;
    return;
  }
  t -= 133120;
  if (t < 131072) {                      // xct guard cols: 4r*8b*128row*2*16slots
    int ch = t & 15, u = t >> 4;
    int hp = (u & 127) + 1; u >>= 7;
    int cs = u & 1; u >>= 1;
    int b = u & 7, r = u >> 3;
    *(f16x8*)&xct[(size_t)r*xct_stride + ((size_t)(b*HP_ + hp)*WP_ + cs*129)*C2_ + ch*8] = z;
  }
}

// ---------- x: NCHW f32 -> padded NHWC f16 (interior rows; guard cols) ------
__global__ void k_xt(const float* __restrict__ x, f16_t* __restrict__ xbt) {
  int wh = blockIdx.x, h = blockIdx.y, b = blockIdx.z;
  int t = threadIdx.x;
  int w0 = wh * 64;
  __shared__ float tile[64][65];
  #pragma unroll
  for (int rep = 0; rep < 16; ++rep) {
    int idx = rep*256 + t;
    int c = idx >> 6, w = idx & 63;
    tile[c][w] = x[((size_t)(b*C_ + c)*H_ + h)*W_ + w0 + w];
  }
  __syncthreads();
  #pragma unroll
  for (int rep = 0; rep < 16; ++rep) {
    int idx = rep*256 + t;
    int w = idx >> 6, c = idx & 63;
    xbt[((size_t)(b*HP_ + h + 1)*WP_ + (w0 + w + 1))*C_ + c] = (f16_t)tile[c][w];
  }
  if (t < 64) {
    if (wh == 0) xbt[((size_t)(b*HP_ + h + 1)*WP_ + 0)*C_ + t]   = (f16_t)0.0f;
    else         xbt[((size_t)(b*HP_ + h + 1)*WP_ + 129)*C_ + t] = (f16_t)0.0f;
  }
}

// ---------- mix1: w1m row = ((rb*2+coh)*2+cb)*64+co6, 288 f16/row -----------
// unit layout within row: s*4 + (cq ^ sig(co6)), each unit = 8 ch f16
__global__ void k_mix1(const float* __restrict__ rw, const float* __restrict__ W1,
                       f16_t* __restrict__ w1m) {
  int gid = blockIdx.x*256 + threadIdx.x;    // 589824 total
  int cq4 = gid & 15;                        // ch quad: ch = cq4*4 .. +3
  int s   = (gid >> 4) % 9;
  int t2  = (gid >> 4) / 9;
  int co  = t2 & 127;
  int rb  = t2 >> 7;                         // 0..31
  float o0=0.f,o1=0.f,o2=0.f,o3=0.f;
  #pragma unroll
  for (int e = 0; e < E_; ++e) {
    float rv = rw[rb*E_ + e];
    const float* wp = W1 + (size_t)((e*C2_ + co)*C_ + cq4*4)*9 + s;
    o0 += rv*wp[0]; o1 += rv*wp[9]; o2 += rv*wp[18]; o3 += rv*wp[27];
  }
  f16x4 pk; pk[0]=(f16_t)o0; pk[1]=(f16_t)o1; pk[2]=(f16_t)o2; pk[3]=(f16_t)o3;
  int coh = co >> 6, co6 = co & 63;
  int cb  = cq4 >> 3;
  int cqu = (cq4 >> 1) & 3;
  int off = (cq4 & 1) * 4;
  size_t row = ((size_t)(rb*2 + coh)*2 + cb)*64 + co6;
  *(f16x4*)&w1m[row*288 + (size_t)(s*4 + (cqu ^ sig(co6)))*8 + off] = pk;
}

// ---------- mix2 (+inline srw): w2m row = (b*4+it)*64+co, 288 f16/row -------
__global__ void k_mix2(const float* __restrict__ pooled, const float* __restrict__ srW,
                       const float* __restrict__ srb, const float* __restrict__ W2,
                       f16_t* __restrict__ w2m, size_t w2m_stride, int r0) {
  const int r = r0 + blockIdx.y;
  const float* pooled_r = pooled + (size_t)r*B_*C2_;
  f16_t* w2m_r = w2m + (size_t)r*w2m_stride;
  __shared__ float sw[64];
  int t = threadIdx.x;
  if (t < 64) {
    int b = t >> 3, e = t & 7;
    float acc = srb[e];
    for (int c = 0; c < C2_; ++c)
      acc += pooled_r[b*C2_ + c] * (1.0f/16384.0f) * srW[c*E_ + e];
    sw[t] = acc;
  }
  __syncthreads();
  int gid = blockIdx.x*256 + t;              // 147456 total
  int c2q = gid & 31;                        // ch quad: ch = c2q*4 .. +3
  int s   = (gid >> 5) % 9;
  int t2  = (gid >> 5) / 9;
  int co  = t2 & 63;
  int b   = t2 >> 6;
  float o0=0.f,o1=0.f,o2=0.f,o3=0.f;
  #pragma unroll
  for (int e = 0; e < E_; ++e) {
    float rv = sw[b*E_ + e];
    const float* wp = W2 + (size_t)((e*C_ + co)*C2_ + c2q*4)*9 + s;
    o0 += rv*wp[0]; o1 += rv*wp[9]; o2 += rv*wp[18]; o3 += rv*wp[27];
  }
  f16x4 pk; pk[0]=(f16_t)o0; pk[1]=(f16_t)o1; pk[2]=(f16_t)o2; pk[3]=(f16_t)o3;
  int it  = c2q >> 3;
  int cqu = (c2q >> 1) & 3;
  int off = (c2q & 1) * 4;
  size_t row = ((size_t)b*4 + it)*64 + co;
  *(f16x4*)&w2m_r[row*288 + (size_t)(s*4 + (cqu ^ sig(co)))*8 + off] = pk;
}

// ---------- conv1: block (b, coh, 2 rows, r): M=64 x N=256 x K=576 ----------
__global__ __launch_bounds__(256, 2) void k_conv1(
    const f16_t* __restrict__ xbt, const f16_t* __restrict__ w1m,
    const float* __restrict__ pa, f16_t* __restrict__ xct, size_t xct_stride,
    float* __restrict__ pooled, int r0)
{
  const int bx = blockIdx.x;
  const int b = bx & 7, h0 = (bx >> 3) << 1;     // b in low bits -> XCD pin
  const int coh = blockIdx.y;
  const int r = r0 + blockIdx.z;
  f16_t* xct_r = xct + (size_t)r*xct_stride;
  float* pooled_r = pooled + (size_t)r*B_*C2_;
  const int tid = threadIdx.x;
  const int lane = tid & 63;
  const int wid = tid >> 6;
  const int wrow = wid >> 1, wph = wid & 1;      // output row, pixel half
  const int l15 = lane & 15, l4 = lane >> 4;
  __shared__ __align__(16) f16_t lA[64*288];     // 36,864 B
  __shared__ __align__(16) f16_t lB[2080*8];     // 33,280 B (total 70,144)

  const int xorA = (l4 ^ sig(l15)) << 4;         // byte offset within A unit group
  int bbase[3];                                  // per-dw B byte base
  #pragma unroll
  for (int dw = 0; dw < 3; ++dw) {
    int P0 = wph*64 + dw + l15;
    bbase[dw] = P0*64 + ((l4 ^ sig(P0)) << 4);
  }

  const f32x4 vzero = {0.f,0.f,0.f,0.f};
  f32x4 acc[4][4];
  #pragma unroll
  for (int i=0;i<4;++i)
    #pragma unroll
    for (int j=0;j<4;++j) acc[i][j] = vzero;

  const int rb = r*B_ + b;
  const f16_t* w1base = w1m + ((size_t)(rb*2 + coh)*2)*64*288;
  const f16_t* xb = xbt + ((size_t)(b*HP_ + h0))*WP_*C_;  // local row 0 = hp h0

  for (int cb = 0; cb < 2; ++cb) {
    __syncthreads();                   // previous reads done / first entry
    // stage A: 2304 linear units (w1m pre-swizzled)
    #pragma unroll
    for (int k = 0; k < 9; ++k) {
      int u = k*256 + tid;
      gl16(w1base + (size_t)cb*64*288 + (size_t)u*8, &lA[u*8]);
    }
    // stage B: 2080 units, per-lane source swizzle, linear LDS dest
    #pragma unroll
    for (int k = 0; k < 8; ++k) {
      int u = k*256 + tid;
      int row = u / 520, rem = u - row*520;
      int pix = rem >> 2, cq = (rem & 3) ^ sig(pix);
      gl16(xb + ((size_t)row*WP_ + pix)*C_ + cb*32 + cq*8, &lB[u*8]);
    }
    if (tid < 32) {                    // tail 32 units
      int u = 2048 + tid;
      int rem = u - 1560;              // row 3
      int pix = rem >> 2, cq = (rem & 3) ^ sig(pix);
      gl16(xb + ((size_t)3*WP_ + pix)*C_ + cb*32 + cq*8, &lB[u*8]);
    }
    __syncthreads();                   // drains vmcnt + barrier
    __builtin_amdgcn_s_setprio(1);
    #pragma unroll
    for (int dh = 0; dh < 3; ++dh) {
      #pragma unroll
      for (int dw = 0; dw < 3; ++dw) {
        const int s = dh*3 + dw;
        f16x8 af[4], bf[4];
        #pragma unroll
        for (int fm = 0; fm < 4; ++fm)
          af[fm] = *(const f16x8*)((const char*)lA + (fm*16 + l15)*576 + s*64 + xorA);
        #pragma unroll
        for (int fn = 0; fn < 4; ++fn)
          bf[fn] = *(const f16x8*)((const char*)lB + (wrow + dh)*8320 + bbase[dw] + fn*1024);
        #pragma unroll
        for (int fm = 0; fm < 4; ++fm)
          #pragma unroll
          for (int fn = 0; fn < 4; ++fn)
            acc[fm][fn] = mfma16(af[fm], bf[fn], acc[fm][fn]);
      }
    }
    __builtin_amdgcn_s_setprio(0);
  }

  // epilogue: PReLU, pooled partials, transpose-store via LDS (reuse lA/lB)
  const float a = pa[0];
  float ps[4][4];
  #pragma unroll
  for (int fm=0;fm<4;++fm)
    #pragma unroll
    for (int j=0;j<4;++j) ps[fm][j] = 0.f;
  #pragma unroll
  for (int fm = 0; fm < 4; ++fm)
    #pragma unroll
    for (int fn = 0; fn < 4; ++fn)
      #pragma unroll
      for (int j = 0; j < 4; ++j) {
        float v = acc[fm][fn][j];
        v = (v >= 0.f) ? v : a*v;
        acc[fm][fn][j] = v;
        ps[fm][j] += v;
      }
  #pragma unroll
  for (int fm = 0; fm < 4; ++fm)
    #pragma unroll
    for (int j = 0; j < 4; ++j) {
      float s = ps[fm][j];
      s += __shfl_xor(s, 1, 64);
      s += __shfl_xor(s, 2, 64);
      s += __shfl_xor(s, 4, 64);
      s += __shfl_xor(s, 8, 64);
      ps[fm][j] = s;                   // valid on l15==0 lanes
    }
  __syncthreads();                     // done reading lA/lB for MFMA
  f16_t* lso = lA;                     // [256 pix][72]
  float* lps = (float*)lB;             // 4 waves x 64 ch partials
  const int prow = wrow*128 + wph*64;
  #pragma unroll
  for (int fm = 0; fm < 4; ++fm)
    #pragma unroll
    for (int fn = 0; fn < 4; ++fn) {
      f16x4 pk;
      #pragma unroll
      for (int j = 0; j < 4; ++j) pk[j] = (f16_t)acc[fm][fn][j];
      *(f16x4*)&lso[(prow + fn*16 + l15)*72 + fm*16 + l4*4] = pk;
    }
  if (l15 == 0) {
    #pragma unroll
    for (int fm = 0; fm < 4; ++fm)
      #pragma unroll
      for (int j = 0; j < 4; ++j)
        lps[wid*64 + fm*16 + l4*4 + j] = ps[fm][j];
  }
  __syncthreads();
  #pragma unroll
  for (int p = 0; p < 8; ++p) {
    int i = p*256 + tid;
    int pl = i >> 3, q = i & 7;
    int row = pl >> 7, pix = pl & 127;
    uint4 v = *(const uint4*)&lso[pl*72 + q*8];
    *(uint4*)(xct_r + ((size_t)(b*HP_ + h0 + row + 1)*WP_ + pix + 1)*C2_ + coh*64 + q*8) = v;
  }
  if (tid < 64) {
    float s = lps[tid] + lps[64 + tid] + lps[128 + tid] + lps[192 + tid];
    atomicAdd(&pooled_r[b*C2_ + coh*64 + tid], s);
  }
}

// ---------- conv2 + PReLU + 1x1 Wout: block (b, 2 rows, r): 64 x 256 x 1152 -
__global__ __launch_bounds__(256, 2) void k_conv2(
    const f16_t* __restrict__ xct, size_t xct_stride,
    const f16_t* __restrict__ w2m, size_t w2m_stride,
    const float* __restrict__ pa, const float* __restrict__ Wout,
    const float* __restrict__ bout, float* __restrict__ out, int r0)
{
  const int bx = blockIdx.x;
  const int b = bx & 7, h0 = (bx >> 3) << 1;
  const int r = r0 + blockIdx.y;
  const int tid = threadIdx.x;
  const int lane = tid & 63;
  const int wid = tid >> 6;
  const int wrow = wid >> 1, wph = wid & 1;
  const int l15 = lane & 15, l4 = lane >> 4;
  __shared__ __align__(16) f16_t lA[64*288];
  __shared__ __align__(16) f16_t lB[2080*8];

  const int xorA = (l4 ^ sig(l15)) << 4;
  int bbase[3];
  #pragma unroll
  for (int dw = 0; dw < 3; ++dw) {
    int P0 = wph*64 + dw + l15;
    bbase[dw] = P0*64 + ((l4 ^ sig(P0)) << 4);
  }

  const f32x4 vzero = {0.f,0.f,0.f,0.f};
  f32x4 acc[4][4];
  #pragma unroll
  for (int i=0;i<4;++i)
    #pragma unroll
    for (int j=0;j<4;++j) acc[i][j] = vzero;

  const f16_t* w2base = w2m + (size_t)r*w2m_stride + (size_t)b*4*64*288;
  const f16_t* xb = xct + (size_t)r*xct_stride + ((size_t)(b*HP_ + h0))*WP_*C2_;

  for (int it = 0; it < 4; ++it) {     // K chunks of 32 ch (over 128)
    __syncthreads();
    #pragma unroll
    for (int k = 0; k < 9; ++k) {
      int u = k*256 + tid;
      gl16(w2base + (size_t)it*64*288 + (size_t)u*8, &lA[u*8]);
    }
    #pragma unroll
    for (int k = 0; k < 8; ++k) {
      int u = k*256 + tid;
      int row = u / 520, rem = u - row*520;
      int pix = rem >> 2, cq = (rem & 3) ^ sig(pix);
      gl16(xb + ((size_t)row*WP_ + pix)*C2_ + it*32 + cq*8, &lB[u*8]);
    }
    if (tid < 32) {
      int u = 2048 + tid;
      int rem = u - 1560;
      int pix = rem >> 2, cq = (rem & 3) ^ sig(pix);
      gl16(xb + ((size_t)3*WP_ + pix)*C2_ + it*32 + cq*8, &lB[u*8]);
    }
    __syncthreads();
    __builtin_amdgcn_s_setprio(1);
    #pragma unroll
    for (int dh = 0; dh < 3; ++dh) {
      #pragma unroll
      for (int dw = 0; dw < 3; ++dw) {
        const int s = dh*3 + dw;
        f16x8 af[4], bf[4];
        #pragma unroll
        for (int fm = 0; fm < 4; ++fm)
          af[fm] = *(const f16x8*)((const char*)lA + (fm*16 + l15)*576 + s*64 + xorA);
        #pragma unroll
        for (int fn = 0; fn < 4; ++fn)
          bf[fn] = *(const f16x8*)((const char*)lB + (wrow + dh)*8320 + bbase[dw] + fn*1024);
        #pragma unroll
        for (int fm = 0; fm < 4; ++fm)
          #pragma unroll
          for (int fn = 0; fn < 4; ++fn)
            acc[fm][fn] = mfma16(af[fm], bf[fn], acc[fm][fn]);
      }
    }
    __builtin_amdgcn_s_setprio(0);
  }

  // epilogue: PReLU + Wout reduce
  const float a  = pa[0];
  const float bo = bout[0];
  float wr_[4][4];
  #pragma unroll
  for (int fm = 0; fm < 4; ++fm)
    #pragma unroll
    for (int j = 0; j < 4; ++j)
      wr_[fm][j] = Wout[fm*16 + l4*4 + j];
  float* orow = out + ((size_t)((b*R_ + r)*H_ + h0 + wrow))*W_;
  #pragma unroll
  for (int fn = 0; fn < 4; ++fn) {
    float s = 0.f;
    #pragma unroll
    for (int fm = 0; fm < 4; ++fm)
      #pragma unroll
      for (int j = 0; j < 4; ++j) {
        float v = acc[fm][fn][j];
        v = (v >= 0.f) ? v : a*v;
        s += wr_[fm][j]*v;
      }
    s += __shfl_xor(s, 16, 64);
    s += __shfl_xor(s, 32, 64);
    if (lane < 16)
      orow[wph*64 + fn*16 + lane] = s + bo;
  }
}

// ---------------------------------------------------------------------------
extern "C" void kernel_launch(void* const* d_in, const int* in_sizes, int n_in,
                              void* d_out, int out_size, void* d_ws, size_t ws_size,
                              hipStream_t stream) {
  (void)in_sizes; (void)n_in; (void)out_size;
  const float* x       = (const float*)d_in[0];
  const float* routing = (const float*)d_in[1];
  const float* rW      = (const float*)d_in[2];
  const float* rB      = (const float*)d_in[3];
  const float* W1      = (const float*)d_in[4];
  const float* pa      = (const float*)d_in[5];
  const float* W2      = (const float*)d_in[6];
  const float* srW     = (const float*)d_in[7];
  const float* srb     = (const float*)d_in[8];
  const float* Wout    = (const float*)d_in[9];
  const float* bout    = (const float*)d_in[10];
  float* out = (float*)d_out;

  const size_t xct_one = (size_t)B_*HP_*WP_*C2_;   // elems (34,611,200 B)
  const size_t w2m_one = (size_t)2048*288;         // elems ( 1,179,648 B)
  // fused needs xbt + w1m + 4*xct + 4*w2m + rw + pooled ~= 165.3 MB
  const size_t need_fused = 17305600ull + 4718592ull + 4*xct_one*2 + 4*w2m_one*2 + 32768ull;
  const bool fused = (ws_size >= need_fused);
  const int ncopies = fused ? 4 : 1;
  const size_t xs = fused ? xct_one : 0;           // per-r strides (elems)
  const size_t ws2 = fused ? w2m_one : 0;

  char* ws = (char*)d_ws;
  size_t off = 0;
  f16_t* xbt = (f16_t*)(ws + off); off += (size_t)B_*HP_*WP_*C_*2;   // 17,305,600
  f16_t* w1m = (f16_t*)(ws + off); off += (size_t)8192*288*2;        //  4,718,592
  f16_t* xct = (f16_t*)(ws + off); off += xct_one*2*ncopies;
  f16_t* w2m = (f16_t*)(ws + off); off += w2m_one*2*ncopies;
  float* rw     = (float*)(ws + off); off += (size_t)R_*B_*E_*4;
  float* pooled = (float*)(ws + off); off += (size_t)R_*B_*C2_*4;

  k_rw  <<<1, 256, 0, stream>>>(routing, rW, rB, rw, pooled);
  k_zero<<<1097, 256, 0, stream>>>(xbt, xct, xs);
  k_xt  <<<dim3(2, H_, B_), 256, 0, stream>>>(x, xbt);
  k_mix1<<<2304, 256, 0, stream>>>(rw, W1, w1m);
  if (fused) {
    k_conv1<<<dim3(512, 2, 4), 256, 0, stream>>>(xbt, w1m, pa, xct, xs, pooled, 0);
    k_mix2 <<<dim3(576, 4), 256, 0, stream>>>(pooled, srW, srb, W2, w2m, ws2, 0);
    k_conv2<<<dim3(512, 4), 256, 0, stream>>>(xct, xs, w2m, ws2, pa, Wout, bout, out, 0);
  } else {
    for (int r = 0; r < R_; ++r) {
      k_conv1<<<dim3(512, 2, 1), 256, 0, stream>>>(xbt, w1m, pa, xct, xs, pooled, r);
      k_mix2 <<<dim3(576, 1), 256, 0, stream>>>(pooled, srW, srb, W2, w2m, ws2, r);
      k_conv2<<<dim3(512, 1), 256, 0, stream>>>(xct, xs, w2m, ws2, pa, Wout, bout, out, r);
    }
  }
}